// Round 17
// baseline (27789.520 us; speedup 1.0000x reference)
//
#include <hip/hip_runtime.h>
#include <hip/hip_bf16.h>
#include <stdint.h>

// Dims
#define STEPS  200
#define KA     1792
#define KD     2560
#define NBLK   256
#define SLOT   (64*2560)
#define RELBASE 256
#define JDA    56          // A frags
#define JDT    80          // D frags total
#define JDL_ATTN 42        // D frags pinned on attn blocks
#define OFF_WD   57344
#define OFF_AWL  100352
#define OFF_OVL  101376
#define OFF_REDG 139264    // red for non-attn blocks
#define DSMEM  159744

using bf16 = __bf16;
typedef __bf16 bf16x8 __attribute__((ext_vector_type(8)));
typedef float  f32x4  __attribute__((ext_vector_type(4)));
typedef unsigned int       u32;
typedef unsigned long long u64;

union U2h { u32 u; bf16 h[2]; };

#define MFMA16(a,b,c) __builtin_amdgcn_mfma_f32_16x16x32_bf16((a),(b),(c),0,0,0)

__device__ __forceinline__ float sigf(float x){ return 1.f/(1.f+__expf(-x)); }
__device__ __forceinline__ float tanhf_(float x){
  float ax = fabsf(x);
  float e  = __expf(-2.f*ax);
  float t  = (1.f-e)/(1.f+e);
  return x < 0.f ? -t : t;
}

// RMW-as-load poll (coherence-point read; R9-proven)
__device__ __forceinline__ u32 atom_peek(u32* p){
  u32 old;
  asm volatile("global_atomic_add %0, %1, %2, off sc0 sc1\n\t"
               "s_waitcnt vmcnt(0)"
               : "=v"(old) : "v"(p), "v"(0u) : "memory");
  return old;
}
__device__ __forceinline__ void stu(u32* p, u32 v){
  __hip_atomic_store(p, v, __ATOMIC_RELAXED, __HIP_MEMORY_SCOPE_AGENT);
}

// ---------------- prologue conversion kernels (R16, proven) ----------------
__global__ void cvt_kernel(const float* __restrict__ s, bf16* __restrict__ d, int n){
  int i = blockIdx.x*256 + threadIdx.x;
  if (i < n) d[i] = (bf16)s[i];
}
__global__ void cvt_pad_kernel(const float* __restrict__ s, bf16* __restrict__ d,
                               int rows, int cin, int cout){
  int i = blockIdx.x*256 + threadIdx.x;
  if (i >= rows*cout) return;
  int r = i / cout, c = i % cout;
  d[i] = (bf16)(c < cin ? s[(size_t)r*cin + c] : 0.f);
}
__global__ void build_wa_pack(const float* __restrict__ Wiha, const float* __restrict__ Whha,
                              bf16* __restrict__ d){
  int i = blockIdx.x*256 + threadIdx.x;
  if (i >= 4096*1792) return;
  int r = i / 1792, k = i % 1792;
  int q2 = r >> 4, g = (r >> 2) & 3, j = r & 3;
  int orig = g*1024 + q2*4 + j;
  float v = (k < 768) ? Wiha[(size_t)orig*768 + k] : Whha[(size_t)orig*1024 + (k - 768)];
  d[i] = (bf16)v;
}
__global__ void build_wd_pack(const float* __restrict__ Wihd, const float* __restrict__ Whhd,
                              bf16* __restrict__ d){
  int i = blockIdx.x*256 + threadIdx.x;
  if (i >= 4096*2560) return;
  int r = i / 2560, k = i % 2560;
  int q2 = r >> 4, g = (r >> 2) & 3, j = r & 3;
  int orig = g*1024 + q2*4 + j;
  float v;
  if (k < 512)        v = Wihd[(size_t)orig*1536 + 1024 + k];
  else if (k < 1536)  v = Wihd[(size_t)orig*1536 + (k - 512)];
  else                v = Whhd[(size_t)orig*1024 + (k - 1536)];
  d[i] = (bf16)v;
}
__global__ void build_wmelcat(const float* __restrict__ Wmel, const float* __restrict__ Wstop,
                              bf16* __restrict__ d){
  int i = blockIdx.x*256 + threadIdx.x;
  if (i >= 176*1536) return;
  int r = i / 1536, c = i % 1536;
  float v = (r < 160) ? Wmel[(size_t)r*1536 + c] : (r == 160 ? Wstop[c] : 0.f);
  d[i] = (bf16)v;
}
__global__ void build_misc2(const float* biha, const float* bhha, float* biasa2,
                            const float* bihd, const float* bhhd, float* biasd2,
                            const float* bmel, const float* bstop, float* bias176,
                            const float* Wloc, float* wlocT){
  int i = blockIdx.x*256 + threadIdx.x;
  if (i < 4096){
    int q2 = i >> 4, g = (i >> 2) & 3, j = i & 3;
    int orig = g*1024 + q2*4 + j;
    biasa2[i] = biha[orig] + bhha[orig];
  } else if (i < 8192){
    int r = i - 4096;
    int q2 = r >> 4, g = (r >> 2) & 3, j = r & 3;
    int orig = g*1024 + q2*4 + j;
    biasd2[r] = bihd[orig] + bhhd[orig];
  } else if (i < 8192+176){
    int j = i - 8192;
    bias176[j] = (j < 160) ? bmel[j] : (j == 160 ? bstop[0] : 0.f);
  } else if (i < 8192+176+4096){
    int t = i - 8368;
    int f = t >> 7, a = t & 127;
    wlocT[t] = Wloc[a*32 + f];
  }
}
__global__ void build_decin(const float* __restrict__ inp, bf16* __restrict__ d){
  int i = blockIdx.x*256 + threadIdx.x;
  if (i >= 12800*96) return;
  int row = i / 96, c = i % 96;
  int s = row >> 6, b = row & 63;
  float v = 0.f;
  if (c < 80 && s > 0) v = inp[((size_t)b*400 + (2*s - 1))*80 + c];
  d[i] = (bf16)v;
}

// ---------------- generic MFMA GEMM (prologue/epilogue) ----------------
template<int ACT, int OBF>
__global__ __launch_bounds__(256)
void gemm_k(const bf16* __restrict__ A, const bf16* __restrict__ Bm,
            const float* __restrict__ bias, float* __restrict__ Cf,
            bf16* __restrict__ Cb, int M, int N, int K, int MT)
{
  int wid = blockIdx.x*4 + (threadIdx.x >> 6);
  if (wid >= MT*(N >> 4)) return;
  int wm = wid % MT, wn = wid / MT;
  int l = threadIdx.x & 63, lo = l & 15, hi = l >> 4;
  const bf16* Bp = Bm + (size_t)(wn*16 + lo)*K + hi*8;
  const bf16* Ap = A  + (size_t)(wm*64 + lo)*K + hi*8;
  f32x4 acc0 = {0,0,0,0}, acc1 = {0,0,0,0}, acc2 = {0,0,0,0}, acc3 = {0,0,0,0};
  for (int k = 0; k < K; k += 32){
    bf16x8 bb = *(const bf16x8*)(Bp + k);
    bf16x8 a0 = *(const bf16x8*)(Ap + k);
    bf16x8 a1 = *(const bf16x8*)(Ap + (size_t)16*K + k);
    bf16x8 a2 = *(const bf16x8*)(Ap + (size_t)32*K + k);
    bf16x8 a3 = *(const bf16x8*)(Ap + (size_t)48*K + k);
    acc0 = MFMA16(a0, bb, acc0);
    acc1 = MFMA16(a1, bb, acc1);
    acc2 = MFMA16(a2, bb, acc2);
    acc3 = MFMA16(a3, bb, acc3);
  }
  int n = wn*16 + lo;
  float bv = bias ? bias[n] : 0.f;
  int m0 = wm*64 + hi*4;
  #pragma unroll
  for (int mt = 0; mt < 4; ++mt){
    f32x4 av = (mt==0)?acc0:(mt==1)?acc1:(mt==2)?acc2:acc3;
    #pragma unroll
    for (int r = 0; r < 4; ++r){
      float v = av[r] + bv;
      if (ACT) v = fmaxf(v, 0.f);
      size_t idx = (size_t)(m0 + mt*16 + r)*N + n;
      if (OBF) Cb[idx] = (bf16)v; else Cf[idx] = v;
    }
  }
}

// ---------------- grid barrier: RMW-polled (R9, proven) ----------------------------
__device__ __forceinline__ void gridbar(unsigned* cnt, unsigned nb){
  __syncthreads();
  const int tid = threadIdx.x;
  if (tid == 0)
    __hip_atomic_fetch_add(&cnt[(blockIdx.x >> 5)*16], 1u, __ATOMIC_RELAXED,
                           __HIP_MEMORY_SCOPE_AGENT);
  if (blockIdx.x == 0){
    if (tid < 64){
      const unsigned tgt = nb*32u;
      for (;;){
        bool ok = true;
        if (tid < 8) ok = (atom_peek(&cnt[tid*16]) >= tgt);
        if (__all(ok)) break;
        __builtin_amdgcn_s_sleep(2);
      }
      __hip_atomic_fetch_add(&cnt[RELBASE + tid*16], 1u, __ATOMIC_RELAXED,
                             __HIP_MEMORY_SCOPE_AGENT);
    }
  } else if (tid == 0){
    u32* rl = &cnt[RELBASE + (blockIdx.x & 63u)*16];
    while (atom_peek(rl) < nb)
      __builtin_amdgcn_s_sleep(2);
  }
  __syncthreads();
}

// ---------------- THE persistent scan kernel: 256 x 1024, 16 waves/CU --------------
// Per block: A-tile bq (16 cols) + D-tile bq, fused gate GEMM + cell (R16 math).
// Weights LDS-pinned (A full; D full on blocks>=64, 42/80 frags on attn blocks,
// tail streamed from L2 ~0.3MB/XCD). Ring transport: sc1 producers, plain
// first-touch consumers (R6). Barriers: RMW-polled (R9). Attn: R15 16-wave body.
__global__ __launch_bounds__(1024)
void decoder_scan(const bf16* __restrict__ pall,
                  const bf16* __restrict__ Wa, const bf16* __restrict__ Wd2,
                  const float* __restrict__ biasa2, const float* __restrict__ biasd2,
                  const bf16* __restrict__ Wqb, const float* __restrict__ Wconv,
                  const float* __restrict__ wlocTg, const float* __restrict__ vvp,
                  const float* __restrict__ pm, const bf16* __restrict__ enc_bf,
                  bf16* __restrict__ ring,
                  float* __restrict__ aC, float* __restrict__ dC,
                  bf16* __restrict__ proj, float* __restrict__ out_attn,
                  unsigned* __restrict__ cnt)
{
  extern __shared__ char smem[];
  const int tid = threadIdx.x;
  const int l = tid & 63, lo = l & 15, hi = l >> 4;
  const int wv = tid >> 6;                 // 0..15
  const int kq = wv & 3, mg = wv >> 2;
  const int m0 = mg * 16;
  const int bq = blockIdx.x;
  const int n0 = bq * 16;
  const bool isAttn = blockIdx.x < 64;
  const int JDL = isAttn ? JDL_ATTN : JDT;

  bf16* wldsA = (bf16*)smem;
  bf16* wldsD = (bf16*)(smem + OFF_WD);
  float* awl  = (float*)(smem + OFF_AWL);
  char*  ovl  = smem + OFF_OVL;
  float* red  = isAttn ? (float*)ovl : (float*)(smem + OFF_REDG);
  // attn overlay (phase-B scratch; red aliases the first 17.4KB)
  bf16*  ahs   = (bf16*)ovl;                   // 2048
  float* locb  = (float*)(ovl + 2048);         // 25600
  float* qp    = (float*)(ovl + 27648);        // 4096
  float* qv    = (float*)(ovl + 31744);        // 512
  float* es    = (float*)(ovl + 32256);        // 1024
  float* sredp = (float*)(ovl + 33280);        // 64
  float* wlocT = (float*)(ovl + 33344);        // 16384 (beyond red: persists)
  float* credx = (float*)(ovl + 49728);        // 4096
  float* credy = (float*)(ovl + 53824);        // 4096

  // ---- init: pin weights to LDS (fragment-major), awl=0, wlocT ----
  for (int j = wv; j < JDA; j += 16)
    *(bf16x8*)(wldsA + ((size_t)(j*64 + l))*8) =
      *(const bf16x8*)(Wa + (size_t)(n0 + lo)*KA + j*32 + hi*8);
  for (int j = wv; j < JDL; j += 16)
    *(bf16x8*)(wldsD + ((size_t)(j*64 + l))*8) =
      *(const bf16x8*)(Wd2 + (size_t)(n0 + lo)*KD + j*32 + hi*8);
  if (isAttn){
    if (tid < 256) awl[tid] = 0.f;
    for (int it = tid; it < 4096; it += 1024) wlocT[it] = wlocTg[it];
  }
  __syncthreads();
  unsigned nb = 0;
  gridbar(cnt, ++nb);

  for (int i = 0; i <= STEPS; ++i){
    const bf16* slotPrev = ring + (size_t)i*SLOT;      // [ctx|ah|dh] of step i-1
    bf16*       slotCur  = ring + (size_t)(i+1)*SLOT;
    const bf16* Xrow = slotPrev + (size_t)(m0 + lo)*2560 + hi*8;

    // =============== phase A: fused gate GEMMs + cells ===============
    if (i < STEPS){
      const bf16* Prow = pall + ((size_t)i*64 + m0 + lo)*256 + hi*8;
      f32x4 acc = {0,0,0,0};
      #pragma unroll
      for (int jj = 0; jj < 14; ++jj){
        int j = kq*14 + jj, k = j*32;
        const bf16* ap = (k < 256) ? (Prow + k) : (Xrow + (k - 256));
        bf16x8 a = *(const bf16x8*)ap;
        bf16x8 b = *(const bf16x8*)(wldsA + ((size_t)(j*64 + l))*8);
        acc = MFMA16(a, b, acc);
      }
      #pragma unroll
      for (int r = 0; r < 4; ++r)
        red[((size_t)kq*64 + m0 + hi*4 + r)*17 + lo] = acc[r];
      __syncthreads();
      if (tid < 128){
        const int b = tid >> 1, jp = (tid & 1)*2;
        U2h hp;
        #pragma unroll
        for (int t = 0; t < 2; ++t){
          int j4 = jp + t;
          float gi = red[(0*64+b)*17+     j4] + red[(1*64+b)*17+     j4] + red[(2*64+b)*17+     j4] + red[(3*64+b)*17+     j4] + biasa2[n0 +      j4];
          float gf = red[(0*64+b)*17+ 4 + j4] + red[(1*64+b)*17+ 4 + j4] + red[(2*64+b)*17+ 4 + j4] + red[(3*64+b)*17+ 4 + j4] + biasa2[n0 +  4 + j4];
          float gg = red[(0*64+b)*17+ 8 + j4] + red[(1*64+b)*17+ 8 + j4] + red[(2*64+b)*17+ 8 + j4] + red[(3*64+b)*17+ 8 + j4] + biasa2[n0 +  8 + j4];
          float go = red[(0*64+b)*17+12 + j4] + red[(1*64+b)*17+12 + j4] + red[(2*64+b)*17+12 + j4] + red[(3*64+b)*17+12 + j4] + biasa2[n0 + 12 + j4];
          float* cp = aC + (size_t)bq*256 + b*4 + j4;
          float c = sigf(gf)*(*cp) + sigf(gi)*tanhf_(gg);
          float h = sigf(go)*tanhf_(c);
          *cp = c;
          hp.h[t] = (bf16)h;
        }
        stu((u32*)(slotCur + (size_t)b*2560 + 512 + bq*4 + jp), hp.u);
      }
      __syncthreads();  // protect red before D writes
    }
    if (i > 0){
      f32x4 acc = {0,0,0,0};
      #pragma unroll
      for (int jj = 0; jj < 20; ++jj){
        int j = kq*20 + jj, k = j*32;
        bf16x8 a = *(const bf16x8*)(Xrow + k);
        bf16x8 b;
        if (j < JDL) b = *(const bf16x8*)(wldsD + ((size_t)(j*64 + l))*8);
        else         b = *(const bf16x8*)(Wd2 + (size_t)(n0 + lo)*KD + k + hi*8);
        acc = MFMA16(a, b, acc);
      }
      #pragma unroll
      for (int r = 0; r < 4; ++r)
        red[((size_t)kq*64 + m0 + hi*4 + r)*17 + lo] = acc[r];
      __syncthreads();
      if (tid < 128){
        const int b = tid >> 1, jp = (tid & 1)*2;
        U2h hp;
        #pragma unroll
        for (int t = 0; t < 2; ++t){
          int j4 = jp + t;
          float gi = red[(0*64+b)*17+     j4] + red[(1*64+b)*17+     j4] + red[(2*64+b)*17+     j4] + red[(3*64+b)*17+     j4] + biasd2[n0 +      j4];
          float gf = red[(0*64+b)*17+ 4 + j4] + red[(1*64+b)*17+ 4 + j4] + red[(2*64+b)*17+ 4 + j4] + red[(3*64+b)*17+ 4 + j4] + biasd2[n0 +  4 + j4];
          float gg = red[(0*64+b)*17+ 8 + j4] + red[(1*64+b)*17+ 8 + j4] + red[(2*64+b)*17+ 8 + j4] + red[(3*64+b)*17+ 8 + j4] + biasd2[n0 +  8 + j4];
          float go = red[(0*64+b)*17+12 + j4] + red[(1*64+b)*17+12 + j4] + red[(2*64+b)*17+12 + j4] + red[(3*64+b)*17+12 + j4] + biasd2[n0 + 12 + j4];
          float* cp = dC + (size_t)bq*256 + b*4 + j4;
          float c = sigf(gf)*(*cp) + sigf(gi)*tanhf_(gg);
          float h = sigf(go)*tanhf_(c);
          *cp = c;
          hp.h[t] = (bf16)h;
        }
        stu((u32*)(slotCur + (size_t)b*2560 + 1536 + bq*4 + jp), hp.u);
        *(u32*)(proj + ((size_t)(i-1)*64 + b)*1536 + bq*4 + jp) = hp.u;
      }
    }
    gridbar(cnt, ++nb);

    // =============== phase B: attention (blocks 0-63, 16 waves) ===============
    if (isAttn && i < STEPS){
      const int b = blockIdx.x;
      if (tid < 128)
        *(bf16x8*)(&ahs[tid*8]) = *(const bf16x8*)(slotCur + (size_t)b*2560 + 512 + tid*8);
      __syncthreads();
      // conv1d(31)
      for (int it = tid; it < 6400; it += 1024){
        int f = it & 31, tl = it >> 5;
        float s = 0.f;
        #pragma unroll
        for (int j = 0; j < 31; ++j){
          int tt = tl + j - 15;
          if ((unsigned)tt < 200u) s += awl[tt]*Wconv[f*31+j];
        }
        locb[tl*32 + f] = s;
      }
      // q = ah @ Wq^T (8 segments)
      {
        int a = tid & 127, seg = tid >> 7;
        const bf16* wr = Wqb + (size_t)a*1024 + seg*128;
        float s = 0.f;
        #pragma unroll
        for (int k2 = 0; k2 < 128; k2 += 8){
          bf16x8 x = *(const bf16x8*)(&ahs[seg*128 + k2]);
          bf16x8 y = *(const bf16x8*)(wr + k2);
          #pragma unroll
          for (int e = 0; e < 8; ++e) s += (float)x[e]*(float)y[e];
        }
        qp[tid] = s;
      }
      __syncthreads();
      if (tid < 128){
        float s = 0.f;
        #pragma unroll
        for (int sg = 0; sg < 8; ++sg) s += qp[tid + sg*128];
        qv[tid] = s;
      }
      __syncthreads();
      // energies
      for (int tl = wv; tl < 200; tl += 16){
        const float* pmrow = pm + ((size_t)b*200 + tl)*128;
        const float* lrow  = locb + tl*32;
        float s = 0.f;
        #pragma unroll
        for (int half = 0; half < 2; ++half){
          int a = l + half*64;
          float x = qv[a] + pmrow[a];
          #pragma unroll
          for (int f = 0; f < 32; ++f) x += lrow[f]*wlocT[f*128 + a];
          s += vvp[a]*tanhf_(x);
        }
        #pragma unroll
        for (int o = 32; o; o >>= 1) s += __shfl_xor(s, o);
        if (l == 0) es[tl] = s;
      }
      __syncthreads();
      // softmax over 200
      {
        float e0 = (tid < 200) ? es[tid] : -3.0e38f;
        float m = e0;
        #pragma unroll
        for (int o = 32; o; o >>= 1) m = fmaxf(m, __shfl_xor(m, o));
        if (l == 0) sredp[wv] = m;
        __syncthreads();
        m = fmaxf(fmaxf(sredp[0],sredp[1]), fmaxf(sredp[2],sredp[3]));
        float p = (tid < 200) ? __expf(e0 - m) : 0.f;
        float ss = p;
        #pragma unroll
        for (int o = 32; o; o >>= 1) ss += __shfl_xor(ss, o);
        __syncthreads();
        if (l == 0) sredp[wv] = ss;
        __syncthreads();
        ss = sredp[0]+sredp[1]+sredp[2]+sredp[3];
        float aval = p / ss;
        if (tid < 256) {
          float nv = (tid < 200) ? aval : 0.f;
          awl[tid] = nv;
        }
        if (tid < 200) out_attn[((size_t)b*200 + i)*200 + tid] = aval;
      }
      __syncthreads();
      // context: 4 t-quarters x 256 cols, LDS reduce
      {
        const int col = tid & 255, tq = tid >> 8;
        const u32* ep = (const u32*)(enc_bf + (size_t)b*102400) + col;
        float x0 = 0.f, y0 = 0.f, x1 = 0.f, y1 = 0.f;
        const int t0 = tq*50;
        #pragma unroll 5
        for (int t = t0; t < t0 + 50; t += 2){
          U2h w0; w0.u = ep[(size_t)t*256];
          U2h w1; w1.u = ep[(size_t)(t+1)*256];
          float a0 = awl[t], a1 = awl[t+1];
          x0 += a0*(float)w0.h[0]; y0 += a0*(float)w0.h[1];
          x1 += a1*(float)w1.h[0]; y1 += a1*(float)w1.h[1];
        }
        credx[tq*256 + col] = x0 + x1;
        credy[tq*256 + col] = y0 + y1;
      }
      __syncthreads();
      if (tid < 256){
        float sx = credx[tid]+credx[256+tid]+credx[512+tid]+credx[768+tid];
        float sy = credy[tid]+credy[256+tid]+credy[512+tid]+credy[768+tid];
        U2h cb; cb.h[0] = (bf16)sx; cb.h[1] = (bf16)sy;
        stu((u32*)(slotCur + (size_t)b*2560) + tid, cb.u);
        *((u32*)(proj + ((size_t)i*64 + b)*1536 + 1024) + tid) = cb.u;
      }
    }
    gridbar(cnt, ++nb);
  }
}

// ---------------- epilogue scatter -------------------------------------------------
__global__ void scatter_out(const float* __restrict__ mt_, float* __restrict__ out){
  int i = blockIdx.x*256 + threadIdx.x;
  const int NMEL = 12800*160;
  if (i < NMEL){
    int sb = i / 160, j = i % 160;
    int s = sb >> 6, b = sb & 63;
    int r = j / 80, mm = j % 80;
    out[((size_t)b*400 + 2*s + r)*80 + mm] = mt_[(size_t)sb*176 + j];
  } else if (i < NMEL + 12800){
    int sb = i - NMEL;
    int s = sb >> 6, b = sb & 63;
    float st = sigf(mt_[(size_t)sb*176 + 160]);
    float* so = out + 2048000;
    so[(size_t)b*400 + 2*s]     = st;
    so[(size_t)b*400 + 2*s + 1] = st;
  }
}

// ==================================================================================
extern "C" void kernel_launch(void* const* d_in, const int* in_sizes, int n_in,
                              void* d_out, int out_size, void* d_ws, size_t ws_size,
                              hipStream_t stream)
{
  const float* enc   = (const float*)d_in[0];
  const float* inp   = (const float*)d_in[1];
  const float* Wpre1 = (const float*)d_in[2];
  const float* bpre1 = (const float*)d_in[3];
  const float* Wpre2 = (const float*)d_in[4];
  const float* bpre2 = (const float*)d_in[5];
  const float* Wmem  = (const float*)d_in[6];
  const float* Wiha  = (const float*)d_in[7];
  const float* Whha  = (const float*)d_in[8];
  const float* biha  = (const float*)d_in[9];
  const float* bhha  = (const float*)d_in[10];
  const float* Wq    = (const float*)d_in[11];
  const float* Wconv = (const float*)d_in[12];
  const float* Wloc  = (const float*)d_in[13];
  const float* vv    = (const float*)d_in[14];
  const float* Wihd  = (const float*)d_in[15];
  const float* Whhd  = (const float*)d_in[16];
  const float* bihd  = (const float*)d_in[17];
  const float* bhhd  = (const float*)d_in[18];
  const float* Wmel  = (const float*)d_in[19];
  const float* bmel  = (const float*)d_in[20];
  const float* Wstop = (const float*)d_in[21];
  const float* bstop = (const float*)d_in[22];
  float* out = (float*)d_out;

  char* pp = (char*)d_ws;
  auto carve = [&](size_t bytes)->char*{
    char* r = (char*)(((uintptr_t)pp + 255) & ~(uintptr_t)255);
    pp = r + bytes;
    return r;
  };
  bf16*  enc_bf  = (bf16*) carve((size_t)64*200*512*2);
  float* pm      = (float*)carve((size_t)64*200*128*4);
  bf16*  decin   = (bf16*) carve((size_t)12800*96*2);
  bf16*  h1      = (bf16*) carve((size_t)12800*256*2);
  bf16*  pall    = (bf16*) carve((size_t)12800*256*2);
  bf16*  Wp1b    = (bf16*) carve((size_t)256*96*2);
  bf16*  Wp2b    = (bf16*) carve((size_t)256*256*2);
  bf16*  Wmemb   = (bf16*) carve((size_t)128*512*2);
  bf16*  Wqb     = (bf16*) carve((size_t)128*1024*2);
  bf16*  Wca     = (bf16*) carve((size_t)4096*KA*2);
  bf16*  Wcd2    = (bf16*) carve((size_t)4096*KD*2);
  bf16*  Wmc     = (bf16*) carve((size_t)176*1536*2);
  float* biasa2  = (float*)carve(4096*4);
  float* biasd2  = (float*)carve(4096*4);
  float* bias176 = (float*)carve(176*4);
  float* wlocTg  = (float*)carve(4096*4);
  bf16*  proj    = (bf16*) carve((size_t)12800*1536*2);
  float* meltmp  = (float*)carve((size_t)12800*176*4);
  // zeroed-every-launch block: cell states + barrier counters
  float* aC  = (float*)carve((size_t)256*64*4*4);
  float* dC  = (float*)carve((size_t)256*64*4*4);
  unsigned* cnt = (unsigned*)carve(16384);
  size_t zbytes = (size_t)((char*)cnt + 16384 - (char*)aC);
  bf16*  ring = (bf16*)carve((size_t)202*SLOT*2);
  hipMemsetAsync(aC, 0, zbytes, stream);
  hipMemsetAsync(ring, 0, (size_t)2*SLOT*2, stream);   // zero slots -1 and 0

  // ---- prologue ----
  cvt_kernel<<<(6553600+255)/256,256,0,stream>>>(enc,   enc_bf, 6553600);
  cvt_kernel<<<(131072+255)/256, 256,0,stream>>>(Wq,    Wqb,    131072);
  cvt_kernel<<<(65536+255)/256,  256,0,stream>>>(Wmem,  Wmemb,  65536);
  cvt_kernel<<<(65536+255)/256,  256,0,stream>>>(Wpre2, Wp2b,   65536);
  cvt_pad_kernel<<<(256*96+255)/256,256,0,stream>>>(Wpre1, Wp1b, 256, 80, 96);
  build_wa_pack<<<(4096*1792+255)/256,256,0,stream>>>(Wiha, Whha, Wca);
  build_wd_pack<<<(4096*2560+255)/256,256,0,stream>>>(Wihd, Whhd, Wcd2);
  build_wmelcat<<<(176*1536+255)/256,256,0,stream>>>(Wmel, Wstop, Wmc);
  build_misc2<<<(8368+4096+255)/256,256,0,stream>>>(biha,bhha,biasa2, bihd,bhhd,biasd2,
                                                    bmel,bstop,bias176, Wloc, wlocTg);
  build_decin<<<(12800*96+255)/256,256,0,stream>>>(inp, decin);

  gemm_k<1,1><<<800,256,0,stream>>>(decin, Wp1b, bpre1, nullptr, h1, 12800,256,96, 200);
  gemm_k<1,1><<<800,256,0,stream>>>(h1, Wp2b, bpre2, nullptr, pall, 12800,256,256, 200);
  gemm_k<0,0><<<400,256,0,stream>>>(enc_bf, Wmemb, nullptr, pm, nullptr, 12800,128,512, 200);

  // ---- persistent scan: 256 blocks x 1024 thr, 16 waves/CU everywhere ----
  hipFuncSetAttribute((const void*)decoder_scan,
                      hipFuncAttributeMaxDynamicSharedMemorySize, DSMEM);
  float* out_attn = out + 2073600;
  decoder_scan<<<NBLK,1024,DSMEM,stream>>>(pall, Wca, Wcd2, biasa2, biasd2,
                                           Wqb, Wconv, wlocTg, vv, pm, enc_bf,
                                           ring, aC, dC, proj, out_attn, cnt);

  // ---- epilogue ----
  gemm_k<0,0><<<550,256,0,stream>>>(proj, Wmc, bias176, meltmp, nullptr, 12800,176,1536, 200);
  scatter_out<<<(12800*160+12800+255)/256,256,0,stream>>>(meltmp, out);
}

// Round 18
// 19777.393 us; speedup vs baseline: 1.4051x; 1.4051x over previous
//
#include <hip/hip_runtime.h>
#include <hip/hip_bf16.h>
#include <stdint.h>

// Dims
#define STEPS  200
#define KA     1792   // p(256) + ctx(512) + ah(1024)
#define KD     2560   // ctx(512) + ah(1024) + dh(1024)  (ring order)
#define SLOT   (64*2560)        // ring slot elements (bf16)

using bf16 = __bf16;
typedef __bf16 bf16x8 __attribute__((ext_vector_type(8)));
typedef float  f32x4  __attribute__((ext_vector_type(4)));
typedef unsigned int       u32;
typedef unsigned long long u64;

union U2h { u32 u; bf16 h[2]; };

#define MFMA16(a,b,c) __builtin_amdgcn_mfma_f32_16x16x32_bf16((a),(b),(c),0,0,0)

__device__ __forceinline__ float sigf(float x){ return 1.f/(1.f+__expf(-x)); }
__device__ __forceinline__ float tanhf_(float x){
  float ax = fabsf(x);
  float e  = __expf(-2.f*ax);
  float t  = (1.f-e)/(1.f+e);
  return x < 0.f ? -t : t;
}

// ---------------- prologue conversion kernels ----------------
__global__ void cvt_kernel(const float* __restrict__ s, bf16* __restrict__ d, int n){
  int i = blockIdx.x*256 + threadIdx.x;
  if (i < n) d[i] = (bf16)s[i];
}
__global__ void cvt_pad_kernel(const float* __restrict__ s, bf16* __restrict__ d,
                               int rows, int cin, int cout){
  int i = blockIdx.x*256 + threadIdx.x;
  if (i >= rows*cout) return;
  int r = i / cout, c = i % cout;
  d[i] = (bf16)(c < cin ? s[(size_t)r*cin + c] : 0.f);
}
// A-weights: packed rows r = q*32 + g*8 + j  <-  orig g*1024 + q*8 + j ; K=[p768|ah1024]
__global__ void build_wa_pack(const float* __restrict__ Wiha, const float* __restrict__ Whha,
                              bf16* __restrict__ d){
  int i = blockIdx.x*256 + threadIdx.x;
  if (i >= 4096*1792) return;
  int r = i / 1792, k = i % 1792;
  int q = r >> 5, g = (r >> 3) & 3, j = r & 7;
  int orig = g*1024 + q*8 + j;
  float v = (k < 768) ? Wiha[(size_t)orig*768 + k] : Whha[(size_t)orig*1024 + (k - 768)];
  d[i] = (bf16)v;
}
// D-weights: packed rows (same permute); K-order [ctx512 | ah1024 | dh1024]
__global__ void build_wd_pack(const float* __restrict__ Wihd, const float* __restrict__ Whhd,
                              bf16* __restrict__ d){
  int i = blockIdx.x*256 + threadIdx.x;
  if (i >= 4096*2560) return;
  int r = i / 2560, k = i % 2560;
  int q = r >> 5, g = (r >> 3) & 3, j = r & 7;
  int orig = g*1024 + q*8 + j;
  float v;
  if (k < 512)        v = Wihd[(size_t)orig*1536 + 1024 + k];
  else if (k < 1536)  v = Wihd[(size_t)orig*1536 + (k - 512)];
  else                v = Whhd[(size_t)orig*1024 + (k - 1536)];
  d[i] = (bf16)v;
}
__global__ void build_wmelcat(const float* __restrict__ Wmel, const float* __restrict__ Wstop,
                              bf16* __restrict__ d){
  int i = blockIdx.x*256 + threadIdx.x;
  if (i >= 176*1536) return;
  int r = i / 1536, c = i % 1536;
  float v = (r < 160) ? Wmel[(size_t)r*1536 + c] : (r == 160 ? Wstop[c] : 0.f);
  d[i] = (bf16)v;
}
// packed biases + mel bias + transposed Wloc
__global__ void build_misc2(const float* biha, const float* bhha, float* biasa2,
                            const float* bihd, const float* bhhd, float* biasd2,
                            const float* bmel, const float* bstop, float* bias176,
                            const float* Wloc, float* wlocT){
  int i = blockIdx.x*256 + threadIdx.x;
  if (i < 4096){
    int q = i >> 5, g = (i >> 3) & 3, j = i & 7;
    int orig = g*1024 + q*8 + j;
    biasa2[i] = biha[orig] + bhha[orig];
  } else if (i < 8192){
    int r = i - 4096;
    int q = r >> 5, g = (r >> 3) & 3, j = r & 7;
    int orig = g*1024 + q*8 + j;
    biasd2[r] = bihd[orig] + bhhd[orig];
  } else if (i < 8192+176){
    int j = i - 8192;
    bias176[j] = (j < 160) ? bmel[j] : (j == 160 ? bstop[0] : 0.f);
  } else if (i < 8192+176+4096){
    int t = i - 8368;                 // t = f*128 + a
    int f = t >> 7, a = t & 127;
    wlocT[t] = Wloc[a*32 + f];
  }
}
__global__ void build_decin(const float* __restrict__ inp, bf16* __restrict__ d){
  int i = blockIdx.x*256 + threadIdx.x;
  if (i >= 12800*96) return;
  int row = i / 96, c = i % 96;
  int s = row >> 6, b = row & 63;
  float v = 0.f;
  if (c < 80 && s > 0) v = inp[((size_t)b*400 + (2*s - 1))*80 + c];
  d[i] = (bf16)v;
}

// ---------------- generic MFMA GEMM (prologue/epilogue batched use) ----------------
template<int ACT, int OBF>
__global__ __launch_bounds__(256)
void gemm_k(const bf16* __restrict__ A, const bf16* __restrict__ Bm,
            const float* __restrict__ bias, float* __restrict__ Cf,
            bf16* __restrict__ Cb, int M, int N, int K, int MT)
{
  int wid = blockIdx.x*4 + (threadIdx.x >> 6);
  if (wid >= MT*(N >> 4)) return;
  int wm = wid % MT, wn = wid / MT;
  int l = threadIdx.x & 63, lo = l & 15, hi = l >> 4;
  const bf16* Bp = Bm + (size_t)(wn*16 + lo)*K + hi*8;
  const bf16* Ap = A  + (size_t)(wm*64 + lo)*K + hi*8;
  f32x4 acc0 = {0,0,0,0}, acc1 = {0,0,0,0}, acc2 = {0,0,0,0}, acc3 = {0,0,0,0};
  for (int k = 0; k < K; k += 32){
    bf16x8 bb = *(const bf16x8*)(Bp + k);
    bf16x8 a0 = *(const bf16x8*)(Ap + k);
    bf16x8 a1 = *(const bf16x8*)(Ap + (size_t)16*K + k);
    bf16x8 a2 = *(const bf16x8*)(Ap + (size_t)32*K + k);
    bf16x8 a3 = *(const bf16x8*)(Ap + (size_t)48*K + k);
    acc0 = MFMA16(a0, bb, acc0);
    acc1 = MFMA16(a1, bb, acc1);
    acc2 = MFMA16(a2, bb, acc2);
    acc3 = MFMA16(a3, bb, acc3);
  }
  int n = wn*16 + lo;
  float bv = bias ? bias[n] : 0.f;
  int m0 = wm*64 + hi*4;
  #pragma unroll
  for (int mt = 0; mt < 4; ++mt){
    f32x4 av = (mt==0)?acc0:(mt==1)?acc1:(mt==2)?acc2:acc3;
    #pragma unroll
    for (int r = 0; r < 4; ++r){
      float v = av[r] + bv;
      if (ACT) v = fmaxf(v, 0.f);
      size_t idx = (size_t)(m0 + mt*16 + r)*N + n;
      if (OBF) Cb[idx] = (bf16)v; else Cf[idx] = v;
    }
  }
}

// ---------------- K1: fused gate-GEMM + LSTM cell, 16 waves/CU --------------------
// 256 blocks x 1024 thr. Blocks 0-127: attn-LSTM(i). Blocks 128-255: dec-LSTM(i-1).
// Wave (kq = wv&3, m-group = wv>>2): K split 4-ways -> LDS partials -> reduce in
// cell update. (R15 configuration: best measured, 19.7 ms end-to-end.)
__global__ __launch_bounds__(1024)
void gates_step(const bf16* __restrict__ pall,
                const bf16* __restrict__ Wa, const bf16* __restrict__ Wd2,
                const float* __restrict__ biasa2, const float* __restrict__ biasd2,
                const bf16* __restrict__ slotPrev, bf16* __restrict__ slotCur,
                float* __restrict__ aC, float* __restrict__ dC,
                bf16* __restrict__ proj, int i, int doA, int doD)
{
  const bool isA = blockIdx.x < 128;
  if (isA ? !doA : !doD) return;
  const int tid = threadIdx.x;
  const int l = tid & 63, lo = l & 15, hi = l >> 4;
  const int wv = tid >> 6;            // 0..15
  const int kq = wv & 3;              // K-quarter
  const int m0 = (wv >> 2) * 16;      // batch-row group
  const int bq = isA ? blockIdx.x : blockIdx.x - 128;
  const int n0 = bq * 32;
  const int K  = isA ? KA : KD;
  const int JQ = isA ? 14 : 20;       // (K/4)/32
  const bf16* Wg = isA ? Wa : Wd2;
  const float* bias2 = isA ? biasa2 : biasd2;
  float* Cst = (isA ? aC : dC) + (size_t)bq*64*8;

  __shared__ float red[4][64][33];    // per-kq partials, +1 pad

  const bf16* Wp0  = Wg + (size_t)(n0 +      lo)*K + hi*8;
  const bf16* Wp1  = Wg + (size_t)(n0 + 16 + lo)*K + hi*8;
  const bf16* Xrow = slotPrev + (size_t)(m0 + lo)*2560 + hi*8;
  const bf16* Prow = pall + ((size_t)i*64 + m0 + lo)*256 + hi*8;
  const int kbase = kq * (K >> 2);
  f32x4 acc0 = {0,0,0,0}, acc1 = {0,0,0,0};
  #pragma unroll 4
  for (int jj = 0; jj < JQ; ++jj){
    int k = kbase + jj*32;
    const bf16* ap;
    if (isA) ap = (k < 256) ? (Prow + k) : (Xrow + (k - 256));
    else     ap = Xrow + k;
    bf16x8 a  = *(const bf16x8*)ap;
    bf16x8 b0 = *(const bf16x8*)(Wp0 + k);
    bf16x8 b1 = *(const bf16x8*)(Wp1 + k);
    acc0 = MFMA16(a, b0, acc0);
    acc1 = MFMA16(a, b1, acc1);
  }
  #pragma unroll
  for (int r = 0; r < 4; ++r){
    red[kq][m0 + hi*4 + r][lo]      = acc0[r];
    red[kq][m0 + hi*4 + r][16 + lo] = acc1[r];
  }
  __syncthreads();
  // cell update: 256 threads -> (batch b = tid>>2, unit pair jp = (tid&3)*2)
  if (tid < 256){
    const int b  = tid >> 2;
    const int jp = (tid & 3)*2;
    U2h hp;
    #pragma unroll
    for (int t = 0; t < 2; ++t){
      int j = jp + t;
      float gi = red[0][b][     j] + red[1][b][     j] + red[2][b][     j] + red[3][b][     j] + bias2[n0 +      j];
      float gf = red[0][b][ 8 + j] + red[1][b][ 8 + j] + red[2][b][ 8 + j] + red[3][b][ 8 + j] + bias2[n0 +  8 + j];
      float gg = red[0][b][16 + j] + red[1][b][16 + j] + red[2][b][16 + j] + red[3][b][16 + j] + bias2[n0 + 16 + j];
      float go = red[0][b][24 + j] + red[1][b][24 + j] + red[2][b][24 + j] + red[3][b][24 + j] + bias2[n0 + 24 + j];
      float* cp = Cst + b*8 + j;
      float c = sigf(gf)*(*cp) + sigf(gi)*tanhf_(gg);
      float h = sigf(go)*tanhf_(c);
      *cp = c;
      hp.h[t] = (bf16)h;
    }
    const int u = bq*8 + jp;
    if (isA){
      *(u32*)(slotCur + (size_t)b*2560 + 512 + u) = hp.u;
    } else {
      *(u32*)(slotCur + (size_t)b*2560 + 1536 + u) = hp.u;
      *(u32*)(proj + ((size_t)(i-1)*64 + b)*1536 + u) = hp.u;   // dh(i-1) -> proj
    }
  }
}

// ---------------- K2: attention, 16 waves/CU --------------------------------------
// 64 blocks x 1024 thr; block = batch. Plain memory, kernel-boundary coherence.
__global__ __launch_bounds__(1024)
void attn_step(const bf16* __restrict__ Wqb, const float* __restrict__ Wconv,
               const float* __restrict__ wlocTg, const float* __restrict__ vvp,
               const float* __restrict__ pm, const bf16* __restrict__ enc_bf,
               const float* __restrict__ alignPrev,   // out_attn base, step i-1
               bf16* __restrict__ slotCur, bf16* __restrict__ proj,
               float* __restrict__ out_attn, int i)
{
  const int tid = threadIdx.x;
  const int l = tid & 63, wv = tid >> 6;
  const int b = blockIdx.x;

  __shared__ __align__(16) bf16 ahs[1024];
  __shared__ float locb[200][32];
  __shared__ float awl[256];
  __shared__ float qp[1024];
  __shared__ float qv[128];
  __shared__ float es[200];
  __shared__ float sred[16];
  __shared__ float wlocT[32][128];
  __shared__ float credx[4][256];
  __shared__ float credy[4][256];

  // stage: align(i-1), wlocT, ah(i)
  if (tid < 256) awl[tid] = 0.f;
  if (i > 0 && tid < 200) awl[tid] = alignPrev[((size_t)b*200 + (i-1))*200 + tid];
  for (int it = tid; it < 4096; it += 1024)
    wlocT[it >> 7][it & 127] = wlocTg[it];
  if (tid < 128)
    *(bf16x8*)(&ahs[tid*8]) = *(const bf16x8*)(slotCur + (size_t)b*2560 + 512 + tid*8);
  __syncthreads();
  // conv1d(31)
  for (int it = tid; it < 6400; it += 1024){
    int f = it & 31, tl = it >> 5;
    float s = 0.f;
    #pragma unroll
    for (int j = 0; j < 31; ++j){
      int tt = tl + j - 15;
      if ((unsigned)tt < 200u) s += awl[tt]*Wconv[f*31+j];
    }
    locb[tl][f] = s;
  }
  // q = ah @ Wq^T  (8 segments of 128 per attn dim)
  {
    int a = tid & 127, seg = tid >> 7;
    const bf16* wr = Wqb + (size_t)a*1024 + seg*128;
    float s = 0.f;
    #pragma unroll
    for (int k2 = 0; k2 < 128; k2 += 8){
      bf16x8 x = *(const bf16x8*)(&ahs[seg*128 + k2]);
      bf16x8 y = *(const bf16x8*)(wr + k2);
      #pragma unroll
      for (int e = 0; e < 8; ++e) s += (float)x[e]*(float)y[e];
    }
    qp[tid] = s;
  }
  __syncthreads();
  if (tid < 128){
    float s = 0.f;
    #pragma unroll
    for (int sg = 0; sg < 8; ++sg) s += qp[tid + sg*128];
    qv[tid] = s;
  }
  __syncthreads();
  // energies (16 waves over 200 rows)
  for (int tl = wv; tl < 200; tl += 16){
    const float* pmrow = pm + ((size_t)b*200 + tl)*128;
    const float* lrow  = locb[tl];
    float s = 0.f;
    #pragma unroll
    for (int half = 0; half < 2; ++half){
      int a = l + half*64;
      float x = qv[a] + pmrow[a];
      #pragma unroll
      for (int f = 0; f < 32; ++f) x += lrow[f]*wlocT[f][a];
      s += vvp[a]*tanhf_(x);
    }
    #pragma unroll
    for (int o = 32; o; o >>= 1) s += __shfl_xor(s, o);
    if (l == 0) es[tl] = s;
  }
  __syncthreads();
  // softmax over 200 (waves 0-3 carry data)
  {
    float e0 = (tid < 200) ? es[tid] : -3.0e38f;
    float m = e0;
    #pragma unroll
    for (int o = 32; o; o >>= 1) m = fmaxf(m, __shfl_xor(m, o));
    if (l == 0) sred[wv] = m;
    __syncthreads();
    m = fmaxf(fmaxf(sred[0],sred[1]), fmaxf(sred[2],sred[3]));
    float p = (tid < 200) ? __expf(e0 - m) : 0.f;
    float ss = p;
    #pragma unroll
    for (int o = 32; o; o >>= 1) ss += __shfl_xor(ss, o);
    __syncthreads();
    if (l == 0) sred[wv] = ss;
    __syncthreads();
    ss = sred[0]+sred[1]+sred[2]+sred[3];
    float aval = p / ss;
    if (tid < 200){
      awl[tid] = aval;
      out_attn[((size_t)b*200 + i)*200 + tid] = aval;
    }
  }
  __syncthreads();
  // context = align @ enc : 4 t-quarters x 256 u32-cols, LDS reduce
  {
    const int col = tid & 255, tq = tid >> 8;
    const u32* ep = (const u32*)(enc_bf + (size_t)b*102400) + col;
    float x0 = 0.f, y0 = 0.f;
    const int t0 = tq*50;
    #pragma unroll 5
    for (int t = t0; t < t0 + 50; ++t){
      U2h w; w.u = ep[(size_t)t*256];
      float al = awl[t];
      x0 += al*(float)w.h[0];
      y0 += al*(float)w.h[1];
    }
    credx[tq][col] = x0;
    credy[tq][col] = y0;
  }
  __syncthreads();
  if (tid < 256){
    float sx = credx[0][tid]+credx[1][tid]+credx[2][tid]+credx[3][tid];
    float sy = credy[0][tid]+credy[1][tid]+credy[2][tid]+credy[3][tid];
    U2h cb; cb.h[0] = (bf16)sx; cb.h[1] = (bf16)sy;
    *((u32*)(slotCur + (size_t)b*2560) + tid) = cb.u;
    *((u32*)(proj + ((size_t)i*64 + b)*1536 + 1024) + tid) = cb.u;
  }
}

// ---------------- epilogue scatter -------------------------------------------------
__global__ void scatter_out(const float* __restrict__ mt_, float* __restrict__ out){
  int i = blockIdx.x*256 + threadIdx.x;
  const int NMEL = 12800*160;
  if (i < NMEL){
    int sb = i / 160, j = i % 160;
    int s = sb >> 6, b = sb & 63;
    int r = j / 80, mm = j % 80;
    out[((size_t)b*400 + 2*s + r)*80 + mm] = mt_[(size_t)sb*176 + j];
  } else if (i < NMEL + 12800){
    int sb = i - NMEL;
    int s = sb >> 6, b = sb & 63;
    float st = sigf(mt_[(size_t)sb*176 + 160]);
    float* so = out + 2048000;
    so[(size_t)b*400 + 2*s]     = st;
    so[(size_t)b*400 + 2*s + 1] = st;
  }
}

// ==================================================================================
extern "C" void kernel_launch(void* const* d_in, const int* in_sizes, int n_in,
                              void* d_out, int out_size, void* d_ws, size_t ws_size,
                              hipStream_t stream)
{
  const float* enc   = (const float*)d_in[0];
  const float* inp   = (const float*)d_in[1];
  const float* Wpre1 = (const float*)d_in[2];
  const float* bpre1 = (const float*)d_in[3];
  const float* Wpre2 = (const float*)d_in[4];
  const float* bpre2 = (const float*)d_in[5];
  const float* Wmem  = (const float*)d_in[6];
  const float* Wiha  = (const float*)d_in[7];
  const float* Whha  = (const float*)d_in[8];
  const float* biha  = (const float*)d_in[9];
  const float* bhha  = (const float*)d_in[10];
  const float* Wq    = (const float*)d_in[11];
  const float* Wconv = (const float*)d_in[12];
  const float* Wloc  = (const float*)d_in[13];
  const float* vv    = (const float*)d_in[14];
  const float* Wihd  = (const float*)d_in[15];
  const float* Whhd  = (const float*)d_in[16];
  const float* bihd  = (const float*)d_in[17];
  const float* bhhd  = (const float*)d_in[18];
  const float* Wmel  = (const float*)d_in[19];
  const float* bmel  = (const float*)d_in[20];
  const float* Wstop = (const float*)d_in[21];
  const float* bstop = (const float*)d_in[22];
  float* out = (float*)d_out;

  char* pp = (char*)d_ws;
  auto carve = [&](size_t bytes)->char*{
    char* r = (char*)(((uintptr_t)pp + 255) & ~(uintptr_t)255);
    pp = r + bytes;
    return r;
  };
  bf16*  enc_bf  = (bf16*) carve((size_t)64*200*512*2);
  float* pm      = (float*)carve((size_t)64*200*128*4);
  bf16*  decin   = (bf16*) carve((size_t)12800*96*2);
  bf16*  h1      = (bf16*) carve((size_t)12800*256*2);
  bf16*  pall    = (bf16*) carve((size_t)12800*256*2);
  bf16*  Wp1b    = (bf16*) carve((size_t)256*96*2);
  bf16*  Wp2b    = (bf16*) carve((size_t)256*256*2);
  bf16*  Wmemb   = (bf16*) carve((size_t)128*512*2);
  bf16*  Wqb     = (bf16*) carve((size_t)128*1024*2);
  bf16*  Wca     = (bf16*) carve((size_t)4096*KA*2);
  bf16*  Wcd2    = (bf16*) carve((size_t)4096*KD*2);
  bf16*  Wmc     = (bf16*) carve((size_t)176*1536*2);
  float* biasa2  = (float*)carve(4096*4);
  float* biasd2  = (float*)carve(4096*4);
  float* bias176 = (float*)carve(176*4);
  float* wlocTg  = (float*)carve(4096*4);
  bf16*  proj    = (bf16*) carve((size_t)12800*1536*2);
  float* meltmp  = (float*)carve((size_t)12800*176*4);
  // zeroed-every-launch block: cell states
  float* aC  = (float*)carve((size_t)128*64*8*4);
  float* dC  = (float*)carve((size_t)128*64*8*4);
  size_t zbytes = (size_t)((char*)dC + (size_t)128*64*8*4 - (char*)aC);
  // write-once activation ring: 202 slots of [64][2560] bf16
  bf16*  ring = (bf16*)carve((size_t)202*SLOT*2);
  hipMemsetAsync(aC, 0, zbytes, stream);
  hipMemsetAsync(ring, 0, (size_t)2*SLOT*2, stream);   // zero slots -1 and 0

  // ---- prologue: conversions / packing ----
  cvt_kernel<<<(6553600+255)/256,256,0,stream>>>(enc,   enc_bf, 6553600);
  cvt_kernel<<<(131072+255)/256, 256,0,stream>>>(Wq,    Wqb,    131072);
  cvt_kernel<<<(65536+255)/256,  256,0,stream>>>(Wmem,  Wmemb,  65536);
  cvt_kernel<<<(65536+255)/256,  256,0,stream>>>(Wpre2, Wp2b,   65536);
  cvt_pad_kernel<<<(256*96+255)/256,256,0,stream>>>(Wpre1, Wp1b, 256, 80, 96);
  build_wa_pack<<<(4096*1792+255)/256,256,0,stream>>>(Wiha, Whha, Wca);
  build_wd_pack<<<(4096*2560+255)/256,256,0,stream>>>(Wihd, Whhd, Wcd2);
  build_wmelcat<<<(176*1536+255)/256,256,0,stream>>>(Wmel, Wstop, Wmc);
  build_misc2<<<(8368+4096+255)/256,256,0,stream>>>(biha,bhha,biasa2, bihd,bhhd,biasd2,
                                                    bmel,bstop,bias176, Wloc, wlocTg);
  build_decin<<<(12800*96+255)/256,256,0,stream>>>(inp, decin);

  // ---- prologue: batched GEMMs ----
  gemm_k<1,1><<<800,256,0,stream>>>(decin, Wp1b, bpre1, nullptr, h1, 12800,256,96, 200);
  gemm_k<1,1><<<800,256,0,stream>>>(h1, Wp2b, bpre2, nullptr, pall, 12800,256,256, 200);
  gemm_k<0,0><<<400,256,0,stream>>>(enc_bf, Wmemb, nullptr, pm, nullptr, 12800,128,512, 200);

  // ---- per-step kernels: coherence via kernel boundaries, 16 waves/CU ----
  float* out_attn = out + 2073600;
  for (int i = 0; i <= STEPS; ++i){
    const bf16* slotPrev = ring + (size_t)i*SLOT;
    bf16*       slotCur  = ring + (size_t)(i+1)*SLOT;
    gates_step<<<256,1024,0,stream>>>(pall, Wca, Wcd2, biasa2, biasd2,
                                      slotPrev, slotCur, aC, dC, proj,
                                      i, i < STEPS ? 1 : 0, i > 0 ? 1 : 0);
    if (i < STEPS)
      attn_step<<<64,1024,0,stream>>>(Wqb, Wconv, wlocTg, vv, pm, enc_bf,
                                      out_attn, slotCur, proj, out_attn, i);
  }

  // ---- epilogue: mel/stop projection + scatter ----
  gemm_k<0,0><<<550,256,0,stream>>>(proj, Wmc, bias176, meltmp, nullptr, 12800,176,1536, 200);
  scatter_out<<<(12800*160+12800+255)/256,256,0,stream>>>(meltmp, out);
}